// Round 1
// baseline (106.290 us; speedup 1.0000x reference)
//
#include <hip/hip_runtime.h>

// Int4 weight-only embedding: out[b,s,:] = (weight[x[b,s],:] - zp_group) * scale_group
// V=128000, D=2048, G=32 (so 64 groups/row), B*S=32768 tokens.
// weight is int4 values stored in int32 containers; scale f32; zp int32; x int32.
// Output f32 (scale dtype). Memory-bound gather: coalesced int4 reads + float4 writes.

#define DIM 2048
#define NGROUPS 64   // D / G = 2048 / 32

__global__ __launch_bounds__(256) void int4_embed_dequant_kernel(
    const int* __restrict__ weight,    // [V, D] int32 (int4 values)
    const float* __restrict__ scale,   // [V, 64] f32
    const int* __restrict__ zp,        // [V, 64] int32
    const int* __restrict__ x,         // [n_tokens] int32
    float* __restrict__ out,           // [n_tokens, D] f32
    int n_tokens)
{
    const int token = blockIdx.x;
    if (token >= n_tokens) return;

    const int row = x[token];               // scalar (wave-uniform) load
    const int t = threadIdx.x;              // 256 threads
    const int d0 = t << 3;                  // 8 channels per thread
    const int g = d0 >> 5;                  // quant group (8 | 32 -> single group/thread)

    const size_t srow = (size_t)row * NGROUPS + g;
    const float s = scale[srow];
    const float z = (float)zp[srow];

    const int4* __restrict__ wrow =
        (const int4*)weight + (size_t)row * (DIM / 4) + (t << 1);
    float4* __restrict__ orow =
        (float4*)out + (size_t)token * (DIM / 4) + (t << 1);

    // two independent 16B loads in flight per lane
    const int4 w0 = wrow[0];
    const int4 w1 = wrow[1];

    float4 o0, o1;
    o0.x = ((float)w0.x - z) * s;
    o0.y = ((float)w0.y - z) * s;
    o0.z = ((float)w0.z - z) * s;
    o0.w = ((float)w0.w - z) * s;
    o1.x = ((float)w1.x - z) * s;
    o1.y = ((float)w1.y - z) * s;
    o1.z = ((float)w1.z - z) * s;
    o1.w = ((float)w1.w - z) * s;

    orow[0] = o0;
    orow[1] = o1;
}

extern "C" void kernel_launch(void* const* d_in, const int* in_sizes, int n_in,
                              void* d_out, int out_size, void* d_ws, size_t ws_size,
                              hipStream_t stream) {
    const int* weight  = (const int*)d_in[0];    // [V, D]
    const float* scale = (const float*)d_in[1];  // [V, 64]
    const int* zp      = (const int*)d_in[2];    // [V, 64]
    const int* x       = (const int*)d_in[3];    // [B*S]

    float* out = (float*)d_out;

    const int n_tokens = in_sizes[3];            // B*S = 32768

    dim3 grid(n_tokens);
    dim3 block(256);
    int4_embed_dequant_kernel<<<grid, block, 0, stream>>>(
        weight, scale, zp, x, out, n_tokens);
}

// Round 3
// 98.676 us; speedup vs baseline: 1.0772x; 1.0772x over previous
//
#include <hip/hip_runtime.h>

// Int4 weight-only embedding: out[b,s,:] = (weight[x[b,s],:] - zp_group) * scale_group
// V=128000, D=2048, G=32 (64 groups/row), B*S=32768 tokens.
// weight int4-in-int32 [V,D]; scale f32 [V,64]; zp int32 [V,64]; x int32 [B*S].
// Output f32. Memory-bound gather.
//
// Round 2 -> 3: fix compile — __builtin_nontemporal_store needs a NATIVE
// vector type (ext_vector_type), not HIP's float4 class. Logic unchanged:
//  - nontemporal 16B stores for out (streaming, no reuse) so the 268 MB write
//    stream doesn't evict the ~237 MB touched-weight set from L3.
//  - persistent grid (2048 blocks = 8/CU x 256 CU), 16 tokens/block, next
//    token's index prefetched one iteration ahead.

#define DIM 2048
#define NGROUPS 64   // D / G

typedef float  f32x4 __attribute__((ext_vector_type(4)));
typedef int    i32x4 __attribute__((ext_vector_type(4)));

__global__ __launch_bounds__(256) void int4_embed_dequant_kernel(
    const int* __restrict__ weight,    // [V, D] int32 (int4 values)
    const float* __restrict__ scale,   // [V, 64] f32
    const int* __restrict__ zp,        // [V, 64] int32
    const int* __restrict__ x,         // [n_tokens] int32
    float* __restrict__ out,           // [n_tokens, D] f32
    int n_tokens)
{
    const int t = threadIdx.x;          // 256 threads, 8 channels each
    const int g = t >> 2;               // quant group = (t*8)/32
    const int stride = gridDim.x;

    int token = blockIdx.x;
    if (token >= n_tokens) return;

    int row = x[token];                 // first index load

    while (token < n_tokens) {
        const int next_token = token + stride;
        // prefetch next index while we gather the current row
        int next_row = 0;
        if (next_token < n_tokens) next_row = x[next_token];

        const size_t srow = (size_t)row * NGROUPS + g;
        const float s = scale[srow];
        const float z = (float)zp[srow];

        const i32x4* __restrict__ wrow =
            (const i32x4*)weight + (size_t)row * (DIM / 4) + (t << 1);
        f32x4* orow =
            (f32x4*)out + (size_t)token * (DIM / 4) + (t << 1);

        const i32x4 w0 = wrow[0];
        const i32x4 w1 = wrow[1];

        f32x4 o0, o1;
        o0.x = ((float)w0.x - z) * s;
        o0.y = ((float)w0.y - z) * s;
        o0.z = ((float)w0.z - z) * s;
        o0.w = ((float)w0.w - z) * s;
        o1.x = ((float)w1.x - z) * s;
        o1.y = ((float)w1.y - z) * s;
        o1.z = ((float)w1.z - z) * s;
        o1.w = ((float)w1.w - z) * s;

        __builtin_nontemporal_store(o0, orow);
        __builtin_nontemporal_store(o1, orow + 1);

        token = next_token;
        row = next_row;
    }
}

extern "C" void kernel_launch(void* const* d_in, const int* in_sizes, int n_in,
                              void* d_out, int out_size, void* d_ws, size_t ws_size,
                              hipStream_t stream) {
    const int* weight  = (const int*)d_in[0];    // [V, D]
    const float* scale = (const float*)d_in[1];  // [V, 64]
    const int* zp      = (const int*)d_in[2];    // [V, 64]
    const int* x       = (const int*)d_in[3];    // [B*S]

    float* out = (float*)d_out;

    const int n_tokens = in_sizes[3];            // B*S = 32768

    // persistent grid: 8 blocks/CU * 256 CU = 2048 -> one residency wave,
    // each block walks 16 tokens.
    int grid = 2048;
    if (grid > n_tokens) grid = n_tokens;

    int4_embed_dequant_kernel<<<dim3(grid), dim3(256), 0, stream>>>(
        weight, scale, zp, x, out, n_tokens);
}

// Round 4
// 98.557 us; speedup vs baseline: 1.0785x; 1.0012x over previous
//
#include <hip/hip_runtime.h>

// Int4 weight-only embedding: out[b,s,:] = (weight[x[b,s],:] - zp_group) * scale_group
// V=128000, D=2048, G=32 (64 groups/row), B*S=32768 tokens.
// weight int4-in-int32 [V,D]; scale f32 [V,64]; zp int32 [V,64]; x int32 [B*S].
// Output f32. Memory-bound gather.
//
// Round 3 -> 4: unroll 2 tokens per loop iteration (deeper MLP: 4x16B weight
// loads in flight per lane instead of 2; 2 index prefetches ahead). Persistent
// grid of 2048 blocks (8/CU), nontemporal output stores kept.

#define DIM 2048
#define NGROUPS 64   // D / G

typedef float  f32x4 __attribute__((ext_vector_type(4)));
typedef int    i32x4 __attribute__((ext_vector_type(4)));

__device__ __forceinline__ void dequant_store(
    const int* __restrict__ weight, const float* __restrict__ scale,
    const int* __restrict__ zp, float* __restrict__ out,
    int row, int token, int t, int g)
{
    const size_t srow = (size_t)row * NGROUPS + g;
    const float s = scale[srow];
    const float z = (float)zp[srow];

    const i32x4* __restrict__ wrow =
        (const i32x4*)weight + (size_t)row * (DIM / 4) + (t << 1);
    f32x4* orow = (f32x4*)out + (size_t)token * (DIM / 4) + (t << 1);

    const i32x4 w0 = wrow[0];
    const i32x4 w1 = wrow[1];

    f32x4 o0, o1;
    o0.x = ((float)w0.x - z) * s;
    o0.y = ((float)w0.y - z) * s;
    o0.z = ((float)w0.z - z) * s;
    o0.w = ((float)w0.w - z) * s;
    o1.x = ((float)w1.x - z) * s;
    o1.y = ((float)w1.y - z) * s;
    o1.z = ((float)w1.z - z) * s;
    o1.w = ((float)w1.w - z) * s;

    __builtin_nontemporal_store(o0, orow);
    __builtin_nontemporal_store(o1, orow + 1);
}

__global__ __launch_bounds__(256) void int4_embed_dequant_kernel(
    const int* __restrict__ weight,    // [V, D] int32 (int4 values)
    const float* __restrict__ scale,   // [V, 64] f32
    const int* __restrict__ zp,        // [V, 64] int32
    const int* __restrict__ x,         // [n_tokens] int32
    float* __restrict__ out,           // [n_tokens, D] f32
    int n_tokens)
{
    const int t = threadIdx.x;          // 256 threads, 8 channels each
    const int g = t >> 2;               // quant group = (t*8)/32
    const int stride = gridDim.x * 2;   // 2 tokens per block per iteration

    int base = blockIdx.x * 2;
    if (base >= n_tokens) return;

    // first pair of indices
    int row0 = x[base];
    int row1 = (base + 1 < n_tokens) ? x[base + 1] : 0;

    while (base < n_tokens) {
        const int nbase = base + stride;
        // prefetch next pair of indices while gathering current rows
        int nrow0 = 0, nrow1 = 0;
        if (nbase < n_tokens) {
            nrow0 = x[nbase];
            if (nbase + 1 < n_tokens) nrow1 = x[nbase + 1];
        }

        dequant_store(weight, scale, zp, out, row0, base, t, g);
        if (base + 1 < n_tokens)
            dequant_store(weight, scale, zp, out, row1, base + 1, t, g);

        base = nbase;
        row0 = nrow0;
        row1 = nrow1;
    }
}

extern "C" void kernel_launch(void* const* d_in, const int* in_sizes, int n_in,
                              void* d_out, int out_size, void* d_ws, size_t ws_size,
                              hipStream_t stream) {
    const int* weight  = (const int*)d_in[0];    // [V, D]
    const float* scale = (const float*)d_in[1];  // [V, 64]
    const int* zp      = (const int*)d_in[2];    // [V, 64]
    const int* x       = (const int*)d_in[3];    // [B*S]

    float* out = (float*)d_out;

    const int n_tokens = in_sizes[3];            // B*S = 32768

    // persistent grid: 8 blocks/CU * 256 CU = 2048 -> one residency wave,
    // each block walks 16 tokens (2 per iteration).
    int grid = 2048;
    int needed = (n_tokens + 1) / 2;
    if (grid > needed) grid = needed;

    int4_embed_dequant_kernel<<<dim3(grid), dim3(256), 0, stream>>>(
        weight, scale, zp, x, out, n_tokens);
}